// Round 1
// baseline (724.462 us; speedup 1.0000x reference)
//
#include <hip/hip_runtime.h>
#include <cstdint>
#include <cstddef>

#define NBUCKET_LOG 17
#define NBUCKET (1 << NBUCKET_LOG)
#define ALPHA 0.4
#define EPS 1e-8

// Workspace layout:
//   [0, 128)        double acc[9]: [0..3] sum eta over events per cause,
//                                  [4..7] sum log(denom) over events per cause,
//                                  [8]    sum logp[label] (CE)
//   [128, 144)      uint cnt[4]: events per cause
//   [4096, 4096+2MB)        float bsum[NBUCKET*4]   (zeroed each launch)
//   [4096+2MB, 4096+4MB)    float suffix[NBUCKET*4] (fully written by scan)

__global__ __launch_bounds__(256) void pass1_kernel(
    const float* __restrict__ log_h, const float* __restrict__ logits,
    const float* __restrict__ dur, const int* __restrict__ ev,
    const int* __restrict__ lab, float* __restrict__ bsum,
    double* __restrict__ acc, unsigned int* __restrict__ cnt, int N)
{
  __shared__ float s_eta[4];
  __shared__ unsigned int s_cnt[4];
  __shared__ float s_ce;
  const int t = threadIdx.x;
  if (t < 4) { s_eta[t] = 0.f; s_cnt[t] = 0u; }
  if (t == 0) s_ce = 0.f;
  __syncthreads();

  const int i = blockIdx.x * 256 + t;
  if (i < N) {
    // ---- eta = clip(mean over 8 heads of log_h[i,:,:], -50, 50) ----
    const float4* ph = (const float4*)(log_h + (size_t)i * 32);
    float m0 = 0.f, m1 = 0.f, m2 = 0.f, m3 = 0.f;
#pragma unroll
    for (int m = 0; m < 8; ++m) {
      float4 v = ph[m];
      m0 += v.x; m1 += v.y; m2 += v.z; m3 += v.w;
    }
    float e0 = fminf(fmaxf(m0 * 0.125f, -50.f), 50.f);
    float e1 = fminf(fmaxf(m1 * 0.125f, -50.f), 50.f);
    float e2 = fminf(fmaxf(m2 * 0.125f, -50.f), 50.f);
    float e3 = fminf(fmaxf(m3 * 0.125f, -50.f), 50.f);
    float x0 = __expf(e0), x1 = __expf(e1), x2 = __expf(e2), x3 = __expf(e3);

    float d = dur[i];
    int b = (int)(d * (float)NBUCKET);
    b = b < 0 ? 0 : (b > NBUCKET - 1 ? NBUCKET - 1 : b);
    float* bp = bsum + (size_t)b * 4;
    unsafeAtomicAdd(bp + 0, x0);
    unsafeAtomicAdd(bp + 1, x1);
    unsafeAtomicAdd(bp + 2, x2);
    unsafeAtomicAdd(bp + 3, x3);

    int e = ev[i];
    if (e > 0) {
      float es = (e == 1) ? e0 : (e == 2) ? e1 : (e == 3) ? e2 : e3;
      atomicAdd(&s_eta[e - 1], es);
      atomicAdd(&s_cnt[e - 1], 1u);
    }

    // ---- cross-entropy on mean logits ----
    const float4* pl = (const float4*)(logits + (size_t)i * 40);
    float buf[40];
#pragma unroll
    for (int j = 0; j < 10; ++j) ((float4*)buf)[j] = pl[j];
    float l0 = 0.f, l1 = 0.f, l2 = 0.f, l3 = 0.f, l4 = 0.f;
#pragma unroll
    for (int m = 0; m < 8; ++m) {
      l0 += buf[m * 5 + 0];
      l1 += buf[m * 5 + 1];
      l2 += buf[m * 5 + 2];
      l3 += buf[m * 5 + 3];
      l4 += buf[m * 5 + 4];
    }
    l0 *= 0.125f; l1 *= 0.125f; l2 *= 0.125f; l3 *= 0.125f; l4 *= 0.125f;
    float mx = fmaxf(fmaxf(fmaxf(l0, l1), fmaxf(l2, l3)), l4);
    float se = __expf(l0 - mx) + __expf(l1 - mx) + __expf(l2 - mx) +
               __expf(l3 - mx) + __expf(l4 - mx);
    float lse = __logf(se) + mx;
    int lb = lab[i];
    float lsel = (lb == 0) ? l0 : (lb == 1) ? l1 : (lb == 2) ? l2 : (lb == 3) ? l3 : l4;
    atomicAdd(&s_ce, lsel - lse);
  }
  __syncthreads();
  if (t < 4) {
    if (s_eta[t] != 0.f) unsafeAtomicAdd(&acc[t], (double)s_eta[t]);
    if (s_cnt[t] != 0u) atomicAdd(&cnt[t], s_cnt[t]);
  }
  if (t == 0 && s_ce != 0.f) unsafeAtomicAdd(&acc[8], (double)s_ce);
}

// Inclusive suffix-sum over NBUCKET buckets (4 causes packed as float4).
// One workgroup of 1024 threads, 128 buckets per thread.
__global__ __launch_bounds__(1024) void scan_kernel(
    const float* __restrict__ bsum, float* __restrict__ suffix)
{
  const int CH = NBUCKET / 1024;  // 128
  const int t = threadIdx.x;
  __shared__ float4 part[1024];
  const float4* in = (const float4*)bsum;
  float4* out = (float4*)suffix;

  float4 a = make_float4(0.f, 0.f, 0.f, 0.f);
  for (int j = 0; j < CH; ++j) {
    float4 v = in[t * CH + j];
    a.x += v.x; a.y += v.y; a.z += v.z; a.w += v.w;
  }
  part[t] = a;
  __syncthreads();
  // Hillis-Steele inclusive suffix scan over the 1024 thread partials
  for (int off = 1; off < 1024; off <<= 1) {
    float4 add = make_float4(0.f, 0.f, 0.f, 0.f);
    if (t + off < 1024) add = part[t + off];
    __syncthreads();
    float4 cur = part[t];
    cur.x += add.x; cur.y += add.y; cur.z += add.z; cur.w += add.w;
    part[t] = cur;
    __syncthreads();
  }
  float4 carry = (t < 1023) ? part[t + 1] : make_float4(0.f, 0.f, 0.f, 0.f);
  for (int j = CH - 1; j >= 0; --j) {
    float4 v = in[t * CH + j];
    carry.x += v.x; carry.y += v.y; carry.z += v.z; carry.w += v.w;
    out[t * CH + j] = carry;
  }
}

__global__ __launch_bounds__(256) void pass3_kernel(
    const float* __restrict__ dur, const int* __restrict__ ev,
    const float* __restrict__ suffix, double* __restrict__ acc, int N)
{
  __shared__ float s_lg[4];
  const int t = threadIdx.x;
  if (t < 4) s_lg[t] = 0.f;
  __syncthreads();
  const int i = blockIdx.x * 256 + t;
  if (i < N) {
    int e = ev[i];
    if (e > 0) {
      float d = dur[i];
      int b = (int)(d * (float)NBUCKET);
      b = b < 0 ? 0 : (b > NBUCKET - 1 ? NBUCKET - 1 : b);
      float rs = suffix[(size_t)b * 4 + (e - 1)];
      atomicAdd(&s_lg[e - 1], __logf(rs + (float)EPS));
    }
  }
  __syncthreads();
  if (t < 4 && s_lg[t] != 0.f) unsafeAtomicAdd(&acc[4 + t], (double)s_lg[t]);
}

__global__ void finalize_kernel(const double* __restrict__ acc,
                                const unsigned int* __restrict__ cnt,
                                float* __restrict__ out, int N)
{
  if (threadIdx.x == 0 && blockIdx.x == 0) {
    double ls = 0.0;
    for (int c = 0; c < 4; ++c) {
      double s = acc[c] - acc[4 + c];           // sum of (eta - log denom)
      ls += -s / ((double)cnt[c] + EPS);
    }
    double ce = -acc[8] / (double)N;
    out[0] = (float)(ALPHA * ls + (1.0 - ALPHA) * ce);
  }
}

extern "C" void kernel_launch(void* const* d_in, const int* in_sizes, int n_in,
                              void* d_out, int out_size, void* d_ws, size_t ws_size,
                              hipStream_t stream) {
  const float* log_h  = (const float*)d_in[0];
  const float* logits = (const float*)d_in[1];
  const float* dur    = (const float*)d_in[2];
  const int*   ev     = (const int*)d_in[3];
  const int*   lab    = (const int*)d_in[4];
  const int N = in_sizes[2];

  char* ws = (char*)d_ws;
  double* acc = (double*)ws;
  unsigned int* cnt = (unsigned int*)(ws + 128);
  float* bsum = (float*)(ws + 4096);
  float* suffix = (float*)(ws + 4096 + (size_t)NBUCKET * 4 * sizeof(float));

  // Zero accumulators + bucket sums (ws is poisoned 0xAA before every launch).
  hipMemsetAsync(ws, 0, 4096 + (size_t)NBUCKET * 4 * sizeof(float), stream);

  const int nb = (N + 255) / 256;
  pass1_kernel<<<nb, 256, 0, stream>>>(log_h, logits, dur, ev, lab, bsum, acc, cnt, N);
  scan_kernel<<<1, 1024, 0, stream>>>(bsum, suffix);
  pass3_kernel<<<nb, 256, 0, stream>>>(dur, ev, suffix, acc, N);
  finalize_kernel<<<1, 1, 0, stream>>>(acc, cnt, (float*)d_out, N);
}

// Round 2
// 393.903 us; speedup vs baseline: 1.8392x; 1.8392x over previous
//
#include <hip/hip_runtime.h>
#include <cstdint>
#include <cstddef>

#define NB2 2048            // duration buckets (uniform [0,1))
#define NCELL (NB2 * 4)     // buckets x 4 causes
#define ALPHA 0.4
#define EPS 1e-8

// Workspace layout:
//   [0,128)    double acc[9]: [0..3] sum eta over events/cause, [4..7] sum log(denom)/cause, [8] CE sum
//   [128,144)  uint cnt[4]
//   [4096, 4096+nparts*32KB)  float partial[nparts][NCELL] (SoA per block: cell = c*NB2+b)
//   then       float histAoS[NCELL]  (AoS: [b*4+c])
//   then       float suffix[NCELL]   (AoS)

__global__ __launch_bounds__(256) void pass1_kernel(
    const float* __restrict__ log_h, const float* __restrict__ logits,
    const float* __restrict__ dur, const int* __restrict__ ev,
    const int* __restrict__ lab, float* __restrict__ partial,
    double* __restrict__ acc, unsigned int* __restrict__ cnt, int N)
{
  __shared__ float h[NCELL];          // 32 KB private histogram, SoA
  __shared__ float s_f[8];
  __shared__ unsigned int s_u[4];
  const int t = threadIdx.x;
  for (int j = t; j < NCELL; j += 256) h[j] = 0.f;
  if (t < 8) s_f[t] = 0.f;
  if (t < 4) s_u[t] = 0u;
  __syncthreads();

  float ce = 0.f;
  float ea0 = 0.f, ea1 = 0.f, ea2 = 0.f, ea3 = 0.f;
  int c0 = 0, c1 = 0, c2 = 0, c3 = 0;

  const int stride = gridDim.x * 256;
  for (int i = blockIdx.x * 256 + t; i < N; i += stride) {
    // ---- eta = clip(mean over 8 heads, -50, 50); exp ----
    const float4* ph = (const float4*)(log_h + (size_t)i * 32);
    float m0 = 0.f, m1 = 0.f, m2 = 0.f, m3 = 0.f;
#pragma unroll
    for (int m = 0; m < 8; ++m) {
      float4 v = ph[m];
      m0 += v.x; m1 += v.y; m2 += v.z; m3 += v.w;
    }
    float e0 = fminf(fmaxf(m0 * 0.125f, -50.f), 50.f);
    float e1 = fminf(fmaxf(m1 * 0.125f, -50.f), 50.f);
    float e2 = fminf(fmaxf(m2 * 0.125f, -50.f), 50.f);
    float e3 = fminf(fmaxf(m3 * 0.125f, -50.f), 50.f);
    float x0 = __expf(e0), x1 = __expf(e1), x2 = __expf(e2), x3 = __expf(e3);

    float d = dur[i];
    int b = (int)(d * (float)NB2);
    b = b < 0 ? 0 : (b > NB2 - 1 ? NB2 - 1 : b);
    atomicAdd(&h[0 * NB2 + b], x0);   // SoA: bank = b%32, conflict-light
    atomicAdd(&h[1 * NB2 + b], x1);
    atomicAdd(&h[2 * NB2 + b], x2);
    atomicAdd(&h[3 * NB2 + b], x3);

    int e = ev[i];
    ea0 += (e == 1) ? e0 : 0.f;  c0 += (e == 1);
    ea1 += (e == 2) ? e1 : 0.f;  c1 += (e == 2);
    ea2 += (e == 3) ? e2 : 0.f;  c2 += (e == 3);
    ea3 += (e == 4) ? e3 : 0.f;  c3 += (e == 4);

    // ---- cross-entropy on mean logits ----
    const float4* pl = (const float4*)(logits + (size_t)i * 40);
    float buf[40];
#pragma unroll
    for (int j = 0; j < 10; ++j) ((float4*)buf)[j] = pl[j];
    float l0 = 0.f, l1 = 0.f, l2 = 0.f, l3 = 0.f, l4 = 0.f;
#pragma unroll
    for (int m = 0; m < 8; ++m) {
      l0 += buf[m * 5 + 0]; l1 += buf[m * 5 + 1]; l2 += buf[m * 5 + 2];
      l3 += buf[m * 5 + 3]; l4 += buf[m * 5 + 4];
    }
    l0 *= 0.125f; l1 *= 0.125f; l2 *= 0.125f; l3 *= 0.125f; l4 *= 0.125f;
    float mx = fmaxf(fmaxf(fmaxf(l0, l1), fmaxf(l2, l3)), l4);
    float se = __expf(l0 - mx) + __expf(l1 - mx) + __expf(l2 - mx) +
               __expf(l3 - mx) + __expf(l4 - mx);
    float lse = __logf(se) + mx;
    int lb = lab[i];
    float lsel = (lb == 0) ? l0 : (lb == 1) ? l1 : (lb == 2) ? l2 : (lb == 3) ? l3 : l4;
    ce += lsel - lse;
  }

  // ---- wave (64-lane) shuffle reductions, then block staging in LDS ----
#define WRED_F(v) { for (int o = 32; o; o >>= 1) v += __shfl_down(v, o); }
#define WRED_I(v) { for (int o = 32; o; o >>= 1) v += __shfl_down(v, o); }
  WRED_F(ea0) WRED_F(ea1) WRED_F(ea2) WRED_F(ea3) WRED_F(ce)
  WRED_I(c0) WRED_I(c1) WRED_I(c2) WRED_I(c3)
  if ((t & 63) == 0) {
    atomicAdd(&s_f[0], ea0); atomicAdd(&s_f[1], ea1);
    atomicAdd(&s_f[2], ea2); atomicAdd(&s_f[3], ea3);
    atomicAdd(&s_f[4], ce);
    atomicAdd(&s_u[0], (unsigned)c0); atomicAdd(&s_u[1], (unsigned)c1);
    atomicAdd(&s_u[2], (unsigned)c2); atomicAdd(&s_u[3], (unsigned)c3);
  }
  __syncthreads();

  // ---- flush private histogram: plain coalesced stores, no atomics ----
  float* out = partial + (size_t)blockIdx.x * NCELL;
  for (int j = t; j < NCELL; j += 256) out[j] = h[j];

  if (t < 4) {
    unsafeAtomicAdd(&acc[t], (double)s_f[t]);
    atomicAdd(&cnt[t], s_u[t]);
  }
  if (t == 4) unsafeAtomicAdd(&acc[8], (double)s_f[4]);
}

// Fold nparts partial histograms (SoA) into one AoS histogram.
// Grid: 256 blocks x 256 threads; block handles 32 cells, 8-way split over partials.
__global__ __launch_bounds__(256) void reduce_kernel(
    const float* __restrict__ partial, float* __restrict__ histAoS, int nparts)
{
  const int tc = threadIdx.x & 31;   // cell within block
  const int tp = threadIdx.x >> 5;   // partial-split 0..7
  const int cell = blockIdx.x * 32 + tc;
  float s = 0.f;
  for (int p = tp; p < nparts; p += 8)
    s += partial[(size_t)p * NCELL + cell];
  __shared__ float sh[256];
  sh[threadIdx.x] = s;
  __syncthreads();
  if (threadIdx.x < 32) {
    float v = 0.f;
#pragma unroll
    for (int k = 0; k < 8; ++k) v += sh[k * 32 + tc];
    int c = cell >> 11;        // cell = c*NB2 + b
    int b = cell & (NB2 - 1);
    histAoS[b * 4 + c] = v;
  }
}

// Inclusive suffix-sum over NB2 buckets (4 causes packed as float4). One WG.
__global__ __launch_bounds__(1024) void scan_kernel(
    const float* __restrict__ hist, float* __restrict__ suffix)
{
  const int CH = NB2 / 1024;   // 2
  const int t = threadIdx.x;
  __shared__ float4 part[1024];
  const float4* in = (const float4*)hist;
  float4* out = (float4*)suffix;

  float4 a = make_float4(0.f, 0.f, 0.f, 0.f);
  for (int j = 0; j < CH; ++j) {
    float4 v = in[t * CH + j];
    a.x += v.x; a.y += v.y; a.z += v.z; a.w += v.w;
  }
  part[t] = a;
  __syncthreads();
  for (int off = 1; off < 1024; off <<= 1) {
    float4 add = make_float4(0.f, 0.f, 0.f, 0.f);
    if (t + off < 1024) add = part[t + off];
    __syncthreads();
    float4 cur = part[t];
    cur.x += add.x; cur.y += add.y; cur.z += add.z; cur.w += add.w;
    part[t] = cur;
    __syncthreads();
  }
  float4 carry = (t < 1023) ? part[t + 1] : make_float4(0.f, 0.f, 0.f, 0.f);
  for (int j = CH - 1; j >= 0; --j) {
    float4 v = in[t * CH + j];
    carry.x += v.x; carry.y += v.y; carry.z += v.z; carry.w += v.w;
    out[t * CH + j] = carry;
  }
}

__global__ __launch_bounds__(256) void pass3_kernel(
    const float* __restrict__ dur, const int* __restrict__ ev,
    const float* __restrict__ suffix, double* __restrict__ acc, int N)
{
  __shared__ float s_lg[4];
  const int t = threadIdx.x;
  if (t < 4) s_lg[t] = 0.f;
  __syncthreads();
  const int i = blockIdx.x * 256 + t;
  if (i < N) {
    int e = ev[i];
    if (e > 0) {
      float d = dur[i];
      int b = (int)(d * (float)NB2);
      b = b < 0 ? 0 : (b > NB2 - 1 ? NB2 - 1 : b);
      float rs = suffix[(size_t)b * 4 + (e - 1)];
      atomicAdd(&s_lg[e - 1], __logf(rs + (float)EPS));
    }
  }
  __syncthreads();
  if (t < 4 && s_lg[t] != 0.f) unsafeAtomicAdd(&acc[4 + t], (double)s_lg[t]);
}

__global__ void finalize_kernel(const double* __restrict__ acc,
                                const unsigned int* __restrict__ cnt,
                                float* __restrict__ out, int N)
{
  if (threadIdx.x == 0 && blockIdx.x == 0) {
    double ls = 0.0;
    for (int c = 0; c < 4; ++c) {
      double s = acc[c] - acc[4 + c];
      ls += -s / ((double)cnt[c] + EPS);
    }
    double ce = -acc[8] / (double)N;
    out[0] = (float)(ALPHA * ls + (1.0 - ALPHA) * ce);
  }
}

extern "C" void kernel_launch(void* const* d_in, const int* in_sizes, int n_in,
                              void* d_out, int out_size, void* d_ws, size_t ws_size,
                              hipStream_t stream) {
  const float* log_h  = (const float*)d_in[0];
  const float* logits = (const float*)d_in[1];
  const float* dur    = (const float*)d_in[2];
  const int*   ev     = (const int*)d_in[3];
  const int*   lab    = (const int*)d_in[4];
  const int N = in_sizes[2];

  const size_t cellBytes = (size_t)NCELL * sizeof(float);   // 32 KB
  // nparts partial histograms must fit after header + hist + suffix
  size_t fixed = 4096 + 2 * cellBytes;
  int nparts = 512;
  if (ws_size > fixed) {
    size_t fit = (ws_size - fixed) / cellBytes;
    if ((size_t)nparts > fit) nparts = (int)fit;
  }
  if (nparts < 1) nparts = 1;

  char* ws = (char*)d_ws;
  double* acc = (double*)ws;
  unsigned int* cnt = (unsigned int*)(ws + 128);
  float* partial = (float*)(ws + 4096);
  float* histAoS = (float*)(ws + 4096 + (size_t)nparts * cellBytes);
  float* suffix  = (float*)(ws + 4096 + (size_t)nparts * cellBytes + cellBytes);

  // Only the 4 KB header needs zeroing; all other ws regions are fully written.
  hipMemsetAsync(ws, 0, 4096, stream);

  pass1_kernel<<<nparts, 256, 0, stream>>>(log_h, logits, dur, ev, lab,
                                           partial, acc, cnt, N);
  reduce_kernel<<<256, 256, 0, stream>>>(partial, histAoS, nparts);
  scan_kernel<<<1, 1024, 0, stream>>>(histAoS, suffix);
  const int nb = (N + 255) / 256;
  pass3_kernel<<<nb, 256, 0, stream>>>(dur, ev, suffix, acc, N);
  finalize_kernel<<<1, 1, 0, stream>>>(acc, cnt, (float*)d_out, N);
}